// Round 1
// baseline (496.456 us; speedup 1.0000x reference)
//
#include <hip/hip_runtime.h>

typedef __bf16 bf16x8 __attribute__((ext_vector_type(8)));
typedef float f32x4 __attribute__((ext_vector_type(4)));

// ---------------------------------------------------------------------------
// Problem constants: B=2, C=512, H=W=64 -> N=4096, 32 groups (16 ch/group)
// ---------------------------------------------------------------------------

// ---------------- GroupNorm stats: one block per (b, group) -----------------
__global__ __launch_bounds__(256) void gn_stats_kernel(const float* __restrict__ x,
                                                       float* __restrict__ mean,
                                                       float* __restrict__ rstd) {
    int gid = blockIdx.x;  // b*32 + g ; channels are 16 per group so base is contiguous
    const float* base = x + (size_t)gid * 16 * 4096;
    float s1 = 0.f, s2 = 0.f;
    for (int i = threadIdx.x; i < 16 * 4096; i += 256) {
        float v = base[i];
        s1 += v;
        s2 += v * v;
    }
    for (int off = 32; off >= 1; off >>= 1) {
        s1 += __shfl_xor(s1, off);
        s2 += __shfl_xor(s2, off);
    }
    __shared__ float r1[4], r2[4];
    int wave = threadIdx.x >> 6, lane = threadIdx.x & 63;
    if (lane == 0) { r1[wave] = s1; r2[wave] = s2; }
    __syncthreads();
    if (threadIdx.x == 0) {
        float S1 = r1[0] + r1[1] + r1[2] + r1[3];
        float S2 = r2[0] + r2[1] + r2[2] + r2[3];
        float m = S1 * (1.f / 65536.f);
        float var = S2 * (1.f / 65536.f) - m * m;
        mean[gid] = m;
        rstd[gid] = rsqrtf(var + 1e-6f);
    }
}

// ------- GroupNorm apply + transpose: x[b][c][n] -> hn_t[b][n][c] bf16 ------
__global__ __launch_bounds__(256) void gn_apply_kernel(const float* __restrict__ x,
                                                       const float* __restrict__ gn_scale,
                                                       const float* __restrict__ gn_bias,
                                                       const float* __restrict__ mean,
                                                       const float* __restrict__ rstd,
                                                       __bf16* __restrict__ hn_t) {
    __shared__ float tile[32][33];
    int b = blockIdx.z;
    int n0 = blockIdx.x * 32, c0 = blockIdx.y * 32;
    int tx = threadIdx.x & 31, ty = threadIdx.x >> 5;  // ty in 0..7
    const float* xb = x + (size_t)b * 512 * 4096;
#pragma unroll
    for (int r = 0; r < 4; ++r) {
        int c = ty + r * 8;
        tile[c][tx] = xb[(size_t)(c0 + c) * 4096 + n0 + tx];
    }
    __syncthreads();
    int c = c0 + tx;
    int g = (b << 5) + (c >> 4);
    float rs = rstd[g];
    float sc = gn_scale[c] * rs;
    float bi = gn_bias[c] - mean[g] * sc;
    __bf16* outp = hn_t + (size_t)b * 4096 * 512;
#pragma unroll
    for (int r = 0; r < 4; ++r) {
        int n = ty + r * 8;
        float v = tile[tx][n];
        outp[(size_t)(n0 + n) * 512 + c] = (__bf16)(v * sc + bi);
    }
}

// ---------------- Weight cast fp32->bf16 + bias pack (bq|bk) ----------------
__global__ __launch_bounds__(256) void cast_weights_kernel(
    const float* __restrict__ wq, const float* __restrict__ wk,
    const float* __restrict__ wv, const float* __restrict__ wp,
    const float* __restrict__ bq, const float* __restrict__ bk,
    __bf16* __restrict__ wqk_b, __bf16* __restrict__ wv_b,
    __bf16* __restrict__ wp_b, float* __restrict__ bqk) {
    int idx = blockIdx.x * 256 + threadIdx.x;  // grid 1024 -> 262144 = 512*512
    wqk_b[idx] = (__bf16)wq[idx];
    wqk_b[262144 + idx] = (__bf16)wk[idx];
    wv_b[idx] = (__bf16)wv[idx];
    wp_b[idx] = (__bf16)wp[idx];
    if (idx < 512) {
        bqk[idx] = bq[idx];
        bqk[512 + idx] = bk[idx];
    }
}

// ---------------------------------------------------------------------------
// Generic tiled MFMA GEMM: C[m][n] = sum_k A[m][k] * Bt[n][k], 64x64 tile.
// A: [M][K] row-major (lda), Bt: [N][K] row-major (ldb). K % 64 == 0.
// OUT_MODE: 0 = bf16 store, 1 = fp16 store (x scale), 2 = fp32 + residual.
// BIAS_MODE: 0 = none, 1 = per-row (M), 2 = per-col (N).
// Fragment layouts (gfx950 mfma_f32_16x16x32_bf16, HW-verified per guide):
//   A/B frag: elem j of lane L = Mat[L&15][(L>>4)*8 + j]  (16B contiguous)
//   C/D     : reg r of lane L = D[(L>>4)*4 + r][L&15]
// ---------------------------------------------------------------------------
template <int OUT_MODE, int BIAS_MODE>
__global__ __launch_bounds__(256) void gemm_kernel(
    const __bf16* __restrict__ A, int lda, long bsA,
    const __bf16* __restrict__ Bt, int ldb, long bsB,
    void* __restrict__ C, int ldc, long bsC,
    const float* __restrict__ bias,
    const float* __restrict__ resid, long bsR,
    int K, float scale) {
    __shared__ __align__(16) __bf16 As[64][72];  // +8 pad: 2-way-max bank aliasing
    __shared__ __align__(16) __bf16 Bs[64][72];

    const int tid = threadIdx.x;
    const int wave = tid >> 6, lane = tid & 63;
    const int q = lane >> 4, ln = lane & 15;
    const int wm = (wave >> 1) << 5, wn = (wave & 1) << 5;  // wave grid 2x2 of 32x32
    const long m0 = (long)blockIdx.y * 64, n0 = (long)blockIdx.x * 64;
    const int b = blockIdx.z;
    A += (long)b * bsA;
    Bt += (long)b * bsB;

    f32x4 acc[2][2] = {};

    for (int k0 = 0; k0 < K; k0 += 64) {
        __syncthreads();
#pragma unroll
        for (int p = 0; p < 2; ++p) {
            int chunk = tid + (p << 8);  // 512 chunks of 8 bf16 per matrix
            int row = chunk >> 3, seg = chunk & 7;
            *(bf16x8*)(&As[row][seg << 3]) =
                *(const bf16x8*)(A + (long)(m0 + row) * lda + k0 + (seg << 3));
            *(bf16x8*)(&Bs[row][seg << 3]) =
                *(const bf16x8*)(Bt + (long)(n0 + row) * ldb + k0 + (seg << 3));
        }
        __syncthreads();
#pragma unroll
        for (int ks = 0; ks < 2; ++ks) {
            bf16x8 af[2], bfr[2];
#pragma unroll
            for (int t = 0; t < 2; ++t) {
                af[t] = *(const bf16x8*)(&As[wm + (t << 4) + ln][(ks << 5) + (q << 3)]);
                bfr[t] = *(const bf16x8*)(&Bs[wn + (t << 4) + ln][(ks << 5) + (q << 3)]);
            }
#pragma unroll
            for (int mt = 0; mt < 2; ++mt)
#pragma unroll
                for (int nt = 0; nt < 2; ++nt)
                    acc[mt][nt] = __builtin_amdgcn_mfma_f32_16x16x32_bf16(
                        af[mt], bfr[nt], acc[mt][nt], 0, 0, 0);
        }
    }

#pragma unroll
    for (int mt = 0; mt < 2; ++mt) {
#pragma unroll
        for (int nt = 0; nt < 2; ++nt) {
            long col = n0 + wn + (nt << 4) + ln;
#pragma unroll
            for (int r = 0; r < 4; ++r) {
                long row = m0 + wm + (mt << 4) + (q << 2) + r;
                float v = acc[mt][nt][r] * scale;
                if (BIAS_MODE == 1) v += bias[row];
                if (BIAS_MODE == 2) v += bias[col];
                long off = (long)b * bsC + row * ldc + col;
                if (OUT_MODE == 0) {
                    ((__bf16*)C)[off] = (__bf16)v;
                } else if (OUT_MODE == 1) {
                    ((_Float16*)C)[off] = (_Float16)v;
                } else {
                    v += resid[(long)b * bsR + row * ldc + col];
                    ((float*)C)[off] = v;
                }
            }
        }
    }
}

// ------------- Row softmax, in place: fp16 logits -> bf16 probs -------------
__global__ __launch_bounds__(256) void softmax_kernel(_Float16* __restrict__ S) {
    long row = blockIdx.x;
    _Float16* srow = S + row * 4096;
    __bf16* prow = (__bf16*)srow;  // same 2B slots, rewritten after full read
    int tid = threadIdx.x;
    float v[16];
    float mx = -1e30f;
#pragma unroll
    for (int p = 0; p < 16; ++p) {
        v[p] = (float)srow[tid + (p << 8)];
        mx = fmaxf(mx, v[p]);
    }
    for (int off = 32; off >= 1; off >>= 1) mx = fmaxf(mx, __shfl_xor(mx, off));
    __shared__ float red[4];
    __shared__ float red2[4];
    int wave = tid >> 6, lane = tid & 63;
    if (lane == 0) red[wave] = mx;
    __syncthreads();
    mx = fmaxf(fmaxf(red[0], red[1]), fmaxf(red[2], red[3]));
    float s = 0.f;
#pragma unroll
    for (int p = 0; p < 16; ++p) {
        v[p] = __expf(v[p] - mx);
        s += v[p];
    }
    for (int off = 32; off >= 1; off >>= 1) s += __shfl_xor(s, off);
    if (lane == 0) red2[wave] = s;
    __syncthreads();
    s = red2[0] + red2[1] + red2[2] + red2[3];
    float inv = 1.f / s;
#pragma unroll
    for (int p = 0; p < 16; ++p) prow[tid + (p << 8)] = (__bf16)(v[p] * inv);
}

// ---------------------------------------------------------------------------
extern "C" void kernel_launch(void* const* d_in, const int* in_sizes, int n_in,
                              void* d_out, int out_size, void* d_ws, size_t ws_size,
                              hipStream_t stream) {
    const float* x = (const float*)d_in[0];
    const float* gn_scale = (const float*)d_in[1];
    const float* gn_bias = (const float*)d_in[2];
    const float* wq = (const float*)d_in[3];
    const float* bq = (const float*)d_in[4];
    const float* wk = (const float*)d_in[5];
    const float* bk = (const float*)d_in[6];
    const float* wv = (const float*)d_in[7];
    const float* bv = (const float*)d_in[8];
    const float* wp = (const float*)d_in[9];
    const float* bp = (const float*)d_in[10];
    float* out = (float*)d_out;

    char* ws = (char*)d_ws;
    // workspace layout (bytes); total ~78 MB
    __bf16* wqk_b = (__bf16*)(ws + 0x0);        // [1024][512] bf16, 1 MB
    __bf16* wv_b = (__bf16*)(ws + 0x100000);    // [512][512]  bf16, 512 KB
    __bf16* wp_b = (__bf16*)(ws + 0x180000);    // [512][512]  bf16, 512 KB
    float* bqk = (float*)(ws + 0x200000);       // [1024] f32
    float* meanb = (float*)(ws + 0x201000);     // [64] f32
    float* rstdb = (float*)(ws + 0x201400);     // [64] f32
    __bf16* hn_t = (__bf16*)(ws + 0x210000);    // [2][4096][512] bf16, 8 MB
    __bf16* qk_t = (__bf16*)(ws + 0xA10000);    // [2][4096][1024] bf16 (q|k), 16 MB
    __bf16* vbuf = (__bf16*)(ws + 0x1A10000);   // [2][512][4096] bf16, 8 MB
    __bf16* o_t = (__bf16*)(ws + 0x2210000);    // [2][4096][512] bf16, 8 MB
    _Float16* Sbuf = (_Float16*)(ws + 0x2A10000);  // [4096][4096] fp16/bf16, 32 MB (per-batch reuse)

    cast_weights_kernel<<<1024, 256, 0, stream>>>(wq, wk, wv, wp, bq, bk,
                                                  wqk_b, wv_b, wp_b, bqk);
    gn_stats_kernel<<<64, 256, 0, stream>>>(x, meanb, rstdb);
    gn_apply_kernel<<<dim3(128, 16, 2), 256, 0, stream>>>(x, gn_scale, gn_bias,
                                                          meanb, rstdb, hn_t);

    // q|k : C[pixel i][d] = sum_c hn_t[i][c] * wqk[d][c] + bias[d]
    gemm_kernel<0, 2><<<dim3(16, 64, 2), 256, 0, stream>>>(
        hn_t, 512, 4096l * 512, wqk_b, 512, 0,
        qk_t, 1024, 4096l * 1024, bqk, nullptr, 0, 512, 1.f);

    // v : C[d][pixel n] = sum_c wv[d][c] * hn_t[n][c] + bv[d]
    gemm_kernel<0, 1><<<dim3(64, 8, 2), 256, 0, stream>>>(
        wv_b, 512, 0, hn_t, 512, 4096l * 512,
        vbuf, 4096, 512l * 4096, bv, nullptr, 0, 512, 1.f);

    const float attn_scale = 0.044194173824159216f;  // 512^-0.5
    for (int b = 0; b < 2; ++b) {
        const __bf16* qb = qk_t + (long)b * 4096 * 1024;
        // S[i][j] = scale * sum_c q_t[i][c] k_t[j][c]   (fp16 out)
        gemm_kernel<1, 0><<<dim3(64, 64, 1), 256, 0, stream>>>(
            qb, 1024, 0, qb + 512, 1024, 0,
            Sbuf, 4096, 0, nullptr, nullptr, 0, 512, attn_scale);
        // row softmax, in place -> bf16 probabilities
        softmax_kernel<<<4096, 256, 0, stream>>>(Sbuf);
        // O_t[i][c] = sum_j P[i][j] * v[c][j]
        gemm_kernel<0, 0><<<dim3(8, 64, 1), 256, 0, stream>>>(
            (const __bf16*)Sbuf, 4096, 0, vbuf + (long)b * 512 * 4096, 4096, 0,
            o_t + (long)b * 4096 * 512, 512, 0, nullptr, nullptr, 0, 4096, 1.f);
    }

    // proj + residual: out[d][n] = sum_c wp[d][c] o_t[n][c] + bp[d] + x[d][n]
    gemm_kernel<2, 1><<<dim3(64, 8, 2), 256, 0, stream>>>(
        wp_b, 512, 0, o_t, 512, 4096l * 512,
        out, 4096, 512l * 4096, bp, x, 512l * 4096, 512, 1.f);
}

// Round 2
// 290.381 us; speedup vs baseline: 1.7097x; 1.7097x over previous
//
#include <hip/hip_runtime.h>

typedef __bf16 bf16x8 __attribute__((ext_vector_type(8)));
typedef float f32x4 __attribute__((ext_vector_type(4)));
typedef _Float16 h8 __attribute__((ext_vector_type(8)));
typedef __bf16 b8v __attribute__((ext_vector_type(8)));

// ---------------------------------------------------------------------------
// Problem constants: B=2, C=512, H=W=64 -> N=4096, 32 groups (16 ch/group)
// ---------------------------------------------------------------------------

// ---------------- async global->LDS 16B copy (m97 technique) ----------------
#if defined(__has_builtin)
#if __has_builtin(__builtin_amdgcn_global_load_lds)
#define HAS_GLL 1
#endif
#endif

__device__ __forceinline__ void async_copy16(const __bf16* g, __bf16* l) {
#ifdef HAS_GLL
    __builtin_amdgcn_global_load_lds(
        (const __attribute__((address_space(1))) unsigned int*)g,
        (__attribute__((address_space(3))) unsigned int*)l, 16, 0, 0);
#else
    *(bf16x8*)l = *(const bf16x8*)g;  // per-lane addresses identical either way
#endif
}

// ------------- GroupNorm stats phase 1: 1024 blocks, float4 loads -----------
// block blk covers 4096 consecutive floats of x; 16 blocks per (b,group).
__global__ __launch_bounds__(256) void gn_partial_kernel(const float* __restrict__ x,
                                                         float* __restrict__ ps) {
    int blk = blockIdx.x;
    const float4* base = (const float4*)x + (size_t)blk * 1024;
    float s1 = 0.f, s2 = 0.f;
#pragma unroll
    for (int i = 0; i < 4; ++i) {
        float4 v = base[threadIdx.x + (i << 8)];
        s1 += v.x + v.y + v.z + v.w;
        s2 += v.x * v.x + v.y * v.y + v.z * v.z + v.w * v.w;
    }
    for (int off = 32; off >= 1; off >>= 1) {
        s1 += __shfl_xor(s1, off);
        s2 += __shfl_xor(s2, off);
    }
    __shared__ float r1[4], r2[4];
    int wave = threadIdx.x >> 6, lane = threadIdx.x & 63;
    if (lane == 0) { r1[wave] = s1; r2[wave] = s2; }
    __syncthreads();
    if (threadIdx.x == 0) {
        ps[blk] = r1[0] + r1[1] + r1[2] + r1[3];
        ps[1024 + blk] = r2[0] + r2[1] + r2[2] + r2[3];
    }
}

// ------------- GroupNorm stats phase 2: 64 groups, tiny finalize ------------
__global__ __launch_bounds__(64) void gn_final_kernel(const float* __restrict__ ps,
                                                      float* __restrict__ mean,
                                                      float* __restrict__ rstd) {
    int g = threadIdx.x;  // 0..63 = b*32+group
    float s1 = 0.f, s2 = 0.f;
#pragma unroll
    for (int i = 0; i < 16; ++i) {
        s1 += ps[g * 16 + i];
        s2 += ps[1024 + g * 16 + i];
    }
    float m = s1 * (1.f / 65536.f);
    float var = s2 * (1.f / 65536.f) - m * m;
    mean[g] = m;
    rstd[g] = rsqrtf(var + 1e-6f);
}

// ------- GroupNorm apply + transpose: x[b][c][n] -> hn_t[b][n][c] bf16 ------
__global__ __launch_bounds__(256) void gn_apply_kernel(const float* __restrict__ x,
                                                       const float* __restrict__ gn_scale,
                                                       const float* __restrict__ gn_bias,
                                                       const float* __restrict__ mean,
                                                       const float* __restrict__ rstd,
                                                       __bf16* __restrict__ hn_t) {
    __shared__ float tile[32][33];
    int b = blockIdx.z;
    int n0 = blockIdx.x * 32, c0 = blockIdx.y * 32;
    int tx = threadIdx.x & 31, ty = threadIdx.x >> 5;  // ty in 0..7
    const float* xb = x + (size_t)b * 512 * 4096;
#pragma unroll
    for (int r = 0; r < 4; ++r) {
        int c = ty + r * 8;
        tile[c][tx] = xb[(size_t)(c0 + c) * 4096 + n0 + tx];
    }
    __syncthreads();
    int c = c0 + tx;
    int g = (b << 5) + (c >> 4);
    float rs = rstd[g];
    float sc = gn_scale[c] * rs;
    float bi = gn_bias[c] - mean[g] * sc;
    __bf16* outp = hn_t + (size_t)b * 4096 * 512;
#pragma unroll
    for (int r = 0; r < 4; ++r) {
        int n = ty + r * 8;
        float v = tile[tx][n];
        outp[(size_t)(n0 + n) * 512 + c] = (__bf16)(v * sc + bi);
    }
}

// ---------------- Weight cast fp32->bf16 + bias pack (bq|bk) ----------------
__global__ __launch_bounds__(256) void cast_weights_kernel(
    const float* __restrict__ wq, const float* __restrict__ wk,
    const float* __restrict__ wv, const float* __restrict__ wp,
    const float* __restrict__ bq, const float* __restrict__ bk,
    __bf16* __restrict__ wqk_b, __bf16* __restrict__ wv_b,
    __bf16* __restrict__ wp_b, float* __restrict__ bqk) {
    int idx = blockIdx.x * 256 + threadIdx.x;  // grid 1024 -> 262144 = 512*512
    wqk_b[idx] = (__bf16)wq[idx];
    wqk_b[262144 + idx] = (__bf16)wk[idx];
    wv_b[idx] = (__bf16)wv[idx];
    wp_b[idx] = (__bf16)wp[idx];
    if (idx < 512) {
        bqk[idx] = bq[idx];
        bqk[512 + idx] = bk[idx];
    }
}

// ---------------------------------------------------------------------------
// m97-style MFMA GEMM: C[m][n] = sum_k A[m][k]*Bt[n][k]. BM=128, BK=64,
// BN template (128 or 64). 256 threads. global_load_lds width-16 staging,
// LDS tiles unpadded + lane-contiguous (required by global_load_lds).
// BN=128: 2x2 waves of 64x64 (4x4 frags). BN=64: 4x1 waves of 32x64 (2x4).
// OUT_MODE: 0=bf16, 1=fp16 (x scale), 2=fp32 + bias + residual.
// BIAS_MODE: 0=none, 1=per-row (M), 2=per-col (N).
// Fragment layouts (gfx950 mfma_f32_16x16x32_bf16, HW-verified per guide):
//   A/B frag: elem j of lane L = Mat[L&15][(L>>4)*8 + j]
//   C/D     : reg r of lane L = D[(L>>4)*4 + r][L&15]
// ---------------------------------------------------------------------------
template <int BN, int OUT_MODE, int BIAS_MODE>
__global__ __launch_bounds__(256) void gemm128_kernel(
    const __bf16* __restrict__ A, int lda, long bsA,
    const __bf16* __restrict__ Bt, int ldb, long bsB,
    void* __restrict__ C, int ldc, long bsC,
    const float* __restrict__ bias,
    const float* __restrict__ resid, long bsR,
    int K, float scale) {
    constexpr int BM = 128;
    constexpr int WM = (BN == 128) ? 64 : 32;
    constexpr int WN = 64;
    constexpr int MT = WM / 16, NT = WN / 16;
    constexpr int WAVES_N = BN / WN;  // 2 or 1
    constexpr int ACH = (BM * 64) / (8 * 256);  // 16B chunks per thread for A = 4
    constexpr int BCH = (BN * 64) / (8 * 256);  // 4 (BN=128) or 2 (BN=64)

    __shared__ __align__(16) __bf16 As[BM][64];
    __shared__ __align__(16) __bf16 Bs[BN][64];

    const int tid = threadIdx.x;
    const int wave = tid >> 6, lane = tid & 63;
    const int q = lane >> 4, ln = lane & 15;
    const int wm = (wave / WAVES_N) * WM;
    const int wn = (wave % WAVES_N) * WN;
    const long m0 = (long)blockIdx.y * BM, n0 = (long)blockIdx.x * BN;
    const int b = blockIdx.z;
    const __bf16* Ab = A + (long)b * bsA + m0 * lda;
    const __bf16* Bb = Bt + (long)b * bsB + n0 * ldb;

    f32x4 acc[MT][NT] = {};

    for (int k0 = 0; k0 < K; k0 += 64) {
        __syncthreads();  // previous iteration's LDS reads done
#pragma unroll
        for (int p = 0; p < ACH; ++p) {
            int c = (p << 8) + tid;  // chunk id; lane-contiguous within a wave
            int row = c >> 3, sg = (c & 7) << 3;
            async_copy16(Ab + (long)row * lda + k0 + sg, &As[0][0] + (c << 3));
        }
#pragma unroll
        for (int p = 0; p < BCH; ++p) {
            int c = (p << 8) + tid;
            int row = c >> 3, sg = (c & 7) << 3;
            async_copy16(Bb + (long)row * ldb + k0 + sg, &Bs[0][0] + (c << 3));
        }
        __syncthreads();  // drains vmcnt (compiler emits waitcnt before barrier)
#pragma unroll
        for (int kk = 0; kk < 2; ++kk) {
            bf16x8 af[MT], bfr[NT];
#pragma unroll
            for (int mt = 0; mt < MT; ++mt)
                af[mt] = *(const bf16x8*)(&As[wm + mt * 16 + ln][(kk << 5) + (q << 3)]);
#pragma unroll
            for (int nt = 0; nt < NT; ++nt)
                bfr[nt] = *(const bf16x8*)(&Bs[wn + nt * 16 + ln][(kk << 5) + (q << 3)]);
#pragma unroll
            for (int mt = 0; mt < MT; ++mt)
#pragma unroll
                for (int nt = 0; nt < NT; ++nt)
                    acc[mt][nt] = __builtin_amdgcn_mfma_f32_16x16x32_bf16(
                        af[mt], bfr[nt], acc[mt][nt], 0, 0, 0);
        }
    }

#pragma unroll
    for (int mt = 0; mt < MT; ++mt) {
#pragma unroll
        for (int nt = 0; nt < NT; ++nt) {
            long col = n0 + wn + nt * 16 + ln;
#pragma unroll
            for (int r = 0; r < 4; ++r) {
                long row = m0 + wm + mt * 16 + (q << 2) + r;
                float v = acc[mt][nt][r] * scale;
                if (BIAS_MODE == 1) v += bias[row];
                if (BIAS_MODE == 2) v += bias[col];
                long off = (long)b * bsC + row * (long)ldc + col;
                if (OUT_MODE == 0) {
                    ((__bf16*)C)[off] = (__bf16)v;
                } else if (OUT_MODE == 1) {
                    ((_Float16*)C)[off] = (_Float16)v;
                } else {
                    ((float*)C)[off] = v + resid[(long)b * bsR + row * (long)ldc + col];
                }
            }
        }
    }
}

// ------------- Row softmax, in place: fp16 logits -> bf16 probs -------------
__global__ __launch_bounds__(256) void softmax_kernel(_Float16* __restrict__ S) {
    long row = blockIdx.x;
    _Float16* srow = S + (row << 12);
    int tid = threadIdx.x;
    h8 a = ((const h8*)srow)[tid];
    h8 c = ((const h8*)srow)[tid + 256];
    float v[16];
    float mx = -1e30f;
#pragma unroll
    for (int p = 0; p < 8; ++p) {
        v[p] = (float)a[p];
        v[8 + p] = (float)c[p];
    }
#pragma unroll
    for (int p = 0; p < 16; ++p) mx = fmaxf(mx, v[p]);
    for (int off = 32; off >= 1; off >>= 1) mx = fmaxf(mx, __shfl_xor(mx, off));
    __shared__ float red[4], red2[4];
    int wave = tid >> 6, lane = tid & 63;
    if (lane == 0) red[wave] = mx;
    __syncthreads();
    mx = fmaxf(fmaxf(red[0], red[1]), fmaxf(red[2], red[3]));
    float s = 0.f;
#pragma unroll
    for (int p = 0; p < 16; ++p) {
        v[p] = __expf(v[p] - mx);
        s += v[p];
    }
    for (int off = 32; off >= 1; off >>= 1) s += __shfl_xor(s, off);
    if (lane == 0) red2[wave] = s;
    __syncthreads();
    s = red2[0] + red2[1] + red2[2] + red2[3];
    float inv = 1.f / s;
    b8v o0, o1;
#pragma unroll
    for (int p = 0; p < 8; ++p) {
        o0[p] = (__bf16)(v[p] * inv);
        o1[p] = (__bf16)(v[8 + p] * inv);
    }
    b8v* prow = (b8v*)srow;  // same 2B slots, rewritten after full read
    prow[tid] = o0;
    prow[tid + 256] = o1;
}

// ---------------------------------------------------------------------------
extern "C" void kernel_launch(void* const* d_in, const int* in_sizes, int n_in,
                              void* d_out, int out_size, void* d_ws, size_t ws_size,
                              hipStream_t stream) {
    const float* x = (const float*)d_in[0];
    const float* gn_scale = (const float*)d_in[1];
    const float* gn_bias = (const float*)d_in[2];
    const float* wq = (const float*)d_in[3];
    const float* bq = (const float*)d_in[4];
    const float* wk = (const float*)d_in[5];
    const float* bk = (const float*)d_in[6];
    const float* wv = (const float*)d_in[7];
    const float* bv = (const float*)d_in[8];
    const float* wp = (const float*)d_in[9];
    const float* bp = (const float*)d_in[10];
    float* out = (float*)d_out;

    char* ws = (char*)d_ws;
    __bf16* wqk_b = (__bf16*)(ws + 0x0);        // [1024][512] bf16, 1 MB
    __bf16* wv_b = (__bf16*)(ws + 0x100000);    // [512][512]  bf16
    __bf16* wp_b = (__bf16*)(ws + 0x180000);    // [512][512]  bf16
    float* bqk = (float*)(ws + 0x200000);       // [1024] f32
    float* meanb = (float*)(ws + 0x201000);     // [64] f32
    float* rstdb = (float*)(ws + 0x201400);     // [64] f32
    float* psum = (float*)(ws + 0x202000);      // [2][1024] f32
    __bf16* hn_t = (__bf16*)(ws + 0x210000);    // [2][4096][512] bf16, 8 MB
    __bf16* qk_t = (__bf16*)(ws + 0xA10000);    // [2][4096][1024] bf16 (q|k), 16 MB
    __bf16* vbuf = (__bf16*)(ws + 0x1A10000);   // [2][512][4096] bf16, 8 MB
    __bf16* o_t = (__bf16*)(ws + 0x2210000);    // [2][4096][512] bf16, 8 MB
    _Float16* Sbuf = (_Float16*)(ws + 0x2A10000);  // [4096][4096] x (1 or 2 batches)

    // can we hold S for both batches (64 MB) -> more parallel S/PV dispatches?
    bool batched = ws_size >= (size_t)0x6A10000;  // 111.2 MB

    cast_weights_kernel<<<1024, 256, 0, stream>>>(wq, wk, wv, wp, bq, bk,
                                                  wqk_b, wv_b, wp_b, bqk);
    gn_partial_kernel<<<1024, 256, 0, stream>>>(x, psum);
    gn_final_kernel<<<1, 64, 0, stream>>>(psum, meanb, rstdb);
    gn_apply_kernel<<<dim3(128, 16, 2), 256, 0, stream>>>(x, gn_scale, gn_bias,
                                                          meanb, rstdb, hn_t);

    // q|k : C[pixel i][d] = sum_c hn_t[i][c]*wqk[d][c] + bqk[d]   (512 blocks)
    gemm128_kernel<128, 0, 2><<<dim3(8, 32, 2), 256, 0, stream>>>(
        hn_t, 512, 4096l * 512, wqk_b, 512, 0,
        qk_t, 1024, 4096l * 1024, bqk, nullptr, 0, 512, 1.f);

    // v : C[d][n] = sum_c wv[d][c]*hn_t[n][c] + bv[d]             (512 blocks)
    gemm128_kernel<64, 0, 1><<<dim3(64, 4, 2), 256, 0, stream>>>(
        wv_b, 512, 0, hn_t, 512, 4096l * 512,
        vbuf, 4096, 512l * 4096, bv, nullptr, 0, 512, 1.f);

    const float attn_scale = 0.044194173824159216f;  // 512^-0.5
    if (batched) {
        // S[b][i][j] = scale * q[i].k[j]  (2048 blocks)
        gemm128_kernel<128, 1, 0><<<dim3(32, 32, 2), 256, 0, stream>>>(
            qk_t, 1024, 4096l * 1024, qk_t + 512, 1024, 4096l * 1024,
            Sbuf, 4096, 4096l * 4096, nullptr, nullptr, 0, 512, attn_scale);
        softmax_kernel<<<8192, 256, 0, stream>>>(Sbuf);
        // O_t[b][i][c] = sum_j P[i][j]*v[c][j]  (512 blocks)
        gemm128_kernel<64, 0, 0><<<dim3(8, 32, 2), 256, 0, stream>>>(
            (const __bf16*)Sbuf, 4096, 4096l * 4096, vbuf, 4096, 512l * 4096,
            o_t, 512, 4096l * 512, nullptr, nullptr, 0, 4096, 1.f);
    } else {
        for (int b = 0; b < 2; ++b) {
            const __bf16* qb = qk_t + (long)b * 4096 * 1024;
            gemm128_kernel<128, 1, 0><<<dim3(32, 32, 1), 256, 0, stream>>>(
                qb, 1024, 0, qb + 512, 1024, 0,
                Sbuf, 4096, 0, nullptr, nullptr, 0, 512, attn_scale);
            softmax_kernel<<<4096, 256, 0, stream>>>(Sbuf);
            gemm128_kernel<64, 0, 0><<<dim3(8, 32, 1), 256, 0, stream>>>(
                (const __bf16*)Sbuf, 4096, 0, vbuf + (long)b * 512 * 4096, 4096, 0,
                o_t + (long)b * 4096 * 512, 512, 0, nullptr, nullptr, 0, 4096, 1.f);
        }
    }

    // proj + residual: out[d][n] = sum_c wp[d][c]*o_t[n][c] + bp[d] + x[d][n]
    gemm128_kernel<64, 2, 1><<<dim3(64, 4, 2), 256, 0, stream>>>(
        wp_b, 512, 0, o_t, 512, 4096l * 512,
        out, 4096, 512l * 4096, bp, x, 512l * 4096, 512, 1.f);
}